// Round 4
// baseline (51.077 us; speedup 1.0000x reference)
//
#include <hip/hip_runtime.h>

#define N_RBF 16
#define N_HIDDEN 32
#define BLOCK 256                       // 4 waves; 2 atoms/block (2 waves per atom)
#define WPB 4
#define QCAP 128                        // per-wave d2 ring buffer (power of 2)

// Gaussian-grid recurrence constants (a = 4.5, w = 1/3):
//   r_k = exp(-a (d - k w)^2) ; r_0 = exp(-a d^2) ; s_k = exp(3d - 0.5 - k)
//   r_{k+1} = r_k * s_k.  Even/odd split: r_{k+2} = r_k * u_k, u_k = s^2 e^{-(2k+1)}
// Chain scaled by 2^80 so r_0 never underflows for d < 5.
#define LOG2E 1.44269504088896340736f
#define NC   (-4.5f * LOG2E)
#define S0A  (3.0f * LOG2E)
#define S0B  (-0.5f * LOG2E)
#define BIAS 80.0f
#define UNSC 8.271806125530277e-25f     // 2^-80
#define C_E1 0.36787944117144233f       // e^-1
#define C_E3 0.049787068367863944f      // e^-3
#define C_E4 0.018315638888734179f      // e^-4

__device__ __forceinline__ void rbf_batch(float d2, bool active, float feat[N_RBF]) {
    float d  = __builtin_amdgcn_sqrtf(d2);
    float r0 = __builtin_amdgcn_exp2f(fmaf(d2, NC, BIAS));   // 2^80 * exp(-a d^2)
    float s  = __builtin_amdgcn_exp2f(fmaf(d, S0A, S0B));    // exp(3d - 0.5)
    float r1 = r0 * s;
    if (!active) { r0 = 0.0f; r1 = 0.0f; }
    float s2 = s * s;
    float ue = s2 * C_E1;
    float uo = s2 * C_E3;
    #pragma unroll
    for (int k = 0; k < N_RBF; k += 2) {
        feat[k]     += r0;
        feat[k + 1] += r1;
        r0 *= ue;  r1 *= uo;
        ue *= C_E4; uo *= C_E4;
    }
}

__global__ __launch_bounds__(256)
void pack_kernel(const float* __restrict__ pos, float4* __restrict__ ppos,
                 int n, int npad)
{
    int i = blockIdx.x * 256 + threadIdx.x;
    if (i < npad) {
        float4 v;
        if (i < n) { v.x = pos[3*i]; v.y = pos[3*i+1]; v.z = pos[3*i+2]; v.w = 0.f; }
        else       { v.x = 1e9f;     v.y = 1e9f;       v.z = 1e9f;       v.w = 0.f; }
        ppos[i] = v;
    }
}

__global__ __launch_bounds__(BLOCK, 8)
void ag3sr_main(const float4* __restrict__ ppos,   // [npad] packed, sentinel-padded
                const float* __restrict__ W1,      // [16,32]
                const float* __restrict__ b1,      // [32]
                const float* __restrict__ W2,      // [32]
                const float* __restrict__ b2,      // [1]
                float* __restrict__ out,           // [1]
                int n, int half)                   // half = npad/2 (multiple of 64)
{
    __shared__ float sq[WPB][QCAP];
    __shared__ float sfeat[WPB][N_RBF];
    __shared__ float sW1[N_RBF * N_HIDDEN];
    __shared__ float sb1[N_HIDDEN], sW2[N_HIDDEN];
    __shared__ float sen[2];

    const int tid    = threadIdx.x;
    const int wave   = tid >> 6;
    const int lane   = tid & 63;
    const int atom   = blockIdx.x * 2 + (wave >> 1);   // 2 atoms per block
    const int halfid = wave & 1;                       // which j-half this wave sweeps

    for (int idx = tid; idx < N_RBF * N_HIDDEN; idx += BLOCK) sW1[idx] = W1[idx];
    if (tid < N_HIDDEN) { sb1[tid] = b1[tid]; sW2[tid] = W2[tid]; }

    float xi = 1e9f, yi = 1e9f, zi = 1e9f;   // sentinel self-pos -> no pairs pass
    if (atom < n) {
        float4 p = ppos[atom];
        xi = p.x; yi = p.y; zi = p.z;
    }

    float feat[N_RBF];
    #pragma unroll
    for (int k = 0; k < N_RBF; ++k) feat[k] = 0.0f;

    int count = 0, processed = 0;
    const int jbase = halfid * half;
    const int iters = half >> 6;

    for (int it = 0; it < iters; ++it) {
        const int j = jbase + (it << 6) + lane;
        float4 p = ppos[j];                         // coalesced dwordx4, L1/L2-hit
        float dx = p.x - xi;
        float dy = p.y - yi;
        float dz = p.z - zi;
        float d2 = dx * dx;
        d2 = fmaf(dy, dy, d2);
        d2 = fmaf(dz, dz, d2);
        bool pass = (d2 > 0.0f) & (d2 < 25.0f);

        unsigned long long m = __ballot(pass);
        unsigned lo = (unsigned)m, hi = (unsigned)(m >> 32);
        int prefix = __builtin_amdgcn_mbcnt_hi(hi, __builtin_amdgcn_mbcnt_lo(lo, 0u));
        if (pass) sq[wave][(count + prefix) & (QCAP - 1)] = d2;
        count += __popcll(m);

        if (count - processed >= 64) {              // wave-uniform drain
            float qd2 = sq[wave][(processed + lane) & (QCAP - 1)];
            processed += 64;
            rbf_batch(qd2, true, feat);
        }
    }

    {   // tail drain (rem in [0,63])
        int rem = count - processed;
        if (rem > 0) {
            bool active = lane < rem;
            float qd2 = active ? sq[wave][(processed + lane) & (QCAP - 1)] : 0.0f;
            rbf_batch(qd2, active, feat);
        }
    }

    // Butterfly-reduce this wave's chunk features; publish to LDS
    #pragma unroll
    for (int k = 0; k < N_RBF; ++k) {
        float v = feat[k];
        #pragma unroll
        for (int off = 32; off > 0; off >>= 1) v += __shfl_xor(v, off, 64);
        feat[k] = v;
    }
    if (lane < N_RBF) sfeat[wave][lane] = feat[lane];
    __syncthreads();

    // Waves 0 and 2 (halfid==0) run the MLP for their atom.
    if (halfid == 0) {
        float e = 0.0f;
        if (lane < N_HIDDEN) {
            float acc = sb1[lane];
            #pragma unroll
            for (int k = 0; k < N_RBF; ++k) {
                float fk = (sfeat[wave][k] + sfeat[wave + 1][k]) * UNSC;
                acc = fmaf(fk, sW1[k * N_HIDDEN + lane], acc);   // LDS broadcast reads
            }
            float sg = 1.0f / (1.0f + __builtin_amdgcn_exp2f(-acc * LOG2E));
            e = acc * sg * sW2[lane];
        }
        #pragma unroll
        for (int off = 16; off > 0; off >>= 1) e += __shfl_xor(e, off, 64);
        if (lane == 0) sen[wave >> 1] = (atom < n) ? (e + b2[0]) : 0.0f;
    }
    __syncthreads();
    if (tid == 0) atomicAdd(out, sen[0] + sen[1]);
}

extern "C" void kernel_launch(void* const* d_in, const int* in_sizes, int n_in,
                              void* d_out, int out_size, void* d_ws, size_t ws_size,
                              hipStream_t stream) {
    const float* pos = (const float*)d_in[0];
    const float* W1  = (const float*)d_in[1];
    const float* b1  = (const float*)d_in[2];
    const float* W2  = (const float*)d_in[3];
    const float* b2  = (const float*)d_in[4];
    float* out = (float*)d_out;

    const int n    = in_sizes[0] / 3;
    const int npad = (n + 127) & ~127;          // multiple of 128 (2 halves of x64)
    const int half = npad >> 1;

    float4* ppos = (float4*)d_ws;               // 16*npad bytes of scratch

    hipMemsetAsync(out, 0, sizeof(float), stream);

    pack_kernel<<<(npad + 255) / 256, 256, 0, stream>>>(pos, ppos, n, npad);

    const int grid = (n + 1) / 2;               // 2 atoms per block
    ag3sr_main<<<grid, BLOCK, 0, stream>>>(ppos, W1, b1, W2, b2, out, n, half);
}

// Round 5
// 38.754 us; speedup vs baseline: 1.3180x; 1.3180x over previous
//
#include <hip/hip_runtime.h>

#define N_RBF 16
#define N_HIDDEN 32
#define BLOCK 256                 // 4 waves per block
#define NW 4
#define APB 4                     // atoms per block, shared by all waves
#define QCAP 128                  // per-(wave,atom) d2 ring (power of 2)

// Gaussian-grid recurrence (a = 4.5, w = 1/3):
//   r_k = exp(-a (d - k w)^2); r_0 = exp(-a d^2); s_k = exp(3d - 0.5 - k)
//   r_{k+1} = r_k * s_k.  Even/odd split: r_{k+2} = r_k * u, u *= e^-4.
// Chain scaled by 2^80 so r_0 never underflows for d < 5.
#define LOG2E 1.44269504088896340736f
#define NC   (-4.5f * LOG2E)
#define S0A  (3.0f * LOG2E)
#define S0B  (-0.5f * LOG2E)
#define BIAS 80.0f
#define UNSC 8.271806125530277e-25f     // 2^-80
#define C_E1 0.36787944117144233f       // e^-1
#define C_E3 0.049787068367863944f      // e^-3
#define C_E4 0.018315638888734179f      // e^-4

__device__ __forceinline__ void rbf_batch(float d2, bool active, float feat[N_RBF]) {
    float d  = __builtin_amdgcn_sqrtf(d2);
    float r0 = __builtin_amdgcn_exp2f(fmaf(d2, NC, BIAS));   // 2^80 * exp(-a d^2)
    float s  = __builtin_amdgcn_exp2f(fmaf(d, S0A, S0B));    // exp(3d - 0.5)
    float r1 = r0 * s;
    if (!active) { r0 = 0.0f; r1 = 0.0f; }
    float s2 = s * s;
    float ue = s2 * C_E1;
    float uo = s2 * C_E3;
    #pragma unroll
    for (int k = 0; k < N_RBF; k += 2) {
        feat[k]     += r0;
        feat[k + 1] += r1;
        r0 *= ue;  r1 *= uo;
        ue *= C_E4; uo *= C_E4;
    }
}

__global__ __launch_bounds__(256)
void pack_kernel(const float* __restrict__ pos, float4* __restrict__ ppos,
                 int n, int npad)
{
    int i = blockIdx.x * 256 + threadIdx.x;
    if (i < npad) {
        float4 v;
        if (i < n) { v.x = pos[3*i]; v.y = pos[3*i+1]; v.z = pos[3*i+2]; v.w = 0.f; }
        else       { v.x = 1e9f;     v.y = 1e9f;       v.z = 1e9f;       v.w = 0.f; }
        ppos[i] = v;
    }
}

__global__ __launch_bounds__(BLOCK, 4)
void ag3sr_main(const float4* __restrict__ ppos,   // [npad] sentinel-padded
                const float* __restrict__ W1,      // [16,32]
                const float* __restrict__ b1,      // [32]
                const float* __restrict__ W2,      // [32]
                const float* __restrict__ b2,      // [1]
                float* __restrict__ out,           // [1]
                int n, int quarter)                // quarter = npad/4 (mult of 64)
{
    __shared__ float sq[NW][APB][QCAP];            // 8 KB
    __shared__ float sfeat[NW][APB][N_RBF];        // 1 KB
    __shared__ float sW1[N_RBF * N_HIDDEN];
    __shared__ float sb1[N_HIDDEN], sW2[N_HIDDEN];
    __shared__ float sen[APB];

    const int tid  = threadIdx.x;
    const int wave = tid >> 6;
    const int lane = tid & 63;
    const int abase = blockIdx.x * APB;

    for (int idx = tid; idx < N_RBF * N_HIDDEN; idx += BLOCK) sW1[idx] = W1[idx];
    if (tid < N_HIDDEN) { sb1[tid] = b1[tid]; sW2[tid] = W2[tid]; }

    // 4 atom positions, wave-uniform (uniform loads -> SGPRs)
    float xi[APB], yi[APB], zi[APB];
    #pragma unroll
    for (int a = 0; a < APB; ++a) {
        float4 p = ppos[abase + a];    // abase+a < npad always (grid from npad)
        xi[a] = p.x; yi[a] = p.y; zi[a] = p.z;
    }

    float feat[APB][N_RBF];
    #pragma unroll
    for (int a = 0; a < APB; ++a)
        #pragma unroll
        for (int k = 0; k < N_RBF; ++k) feat[a][k] = 0.0f;

    int count[APB], proc[APB];
    #pragma unroll
    for (int a = 0; a < APB; ++a) { count[a] = 0; proc[a] = 0; }

    const int jbase = wave * quarter;
    const int iters = quarter >> 6;

    #pragma unroll 2
    for (int it = 0; it < iters; ++it) {
        const int j = jbase + (it << 6) + lane;
        float4 p = ppos[j];                    // 1 load serves 4*64 = 256 pairs
        #pragma unroll
        for (int a = 0; a < APB; ++a) {
            float dx = p.x - xi[a];
            float dy = p.y - yi[a];
            float dz = p.z - zi[a];
            float d2 = dx * dx;
            d2 = fmaf(dy, dy, d2);
            d2 = fmaf(dz, dz, d2);
            bool pass = (d2 > 0.0f) & (d2 < 25.0f);

            unsigned long long m = __ballot(pass);
            unsigned lo = (unsigned)m, hi = (unsigned)(m >> 32);
            int prefix = __builtin_amdgcn_mbcnt_hi(hi, __builtin_amdgcn_mbcnt_lo(lo, 0u));
            if (pass) sq[wave][a][(count[a] + prefix) & (QCAP - 1)] = d2;
            count[a] += __popcll(m);

            if (count[a] - proc[a] >= 64) {    // wave-uniform drain
                float qd2 = sq[wave][a][(proc[a] + lane) & (QCAP - 1)];
                proc[a] += 64;
                rbf_batch(qd2, true, feat[a]);
            }
        }
    }

    // tail drains
    #pragma unroll
    for (int a = 0; a < APB; ++a) {
        int rem = count[a] - proc[a];
        if (rem > 0) {
            bool active = lane < rem;
            float qd2 = active ? sq[wave][a][(proc[a] + lane) & (QCAP - 1)] : 0.0f;
            rbf_batch(qd2, active, feat[a]);
        }
    }

    // Transpose-reduce 16 feats across 64 lanes (32 shuffles/atom, not 96):
    // fold upper/lower halves across lane bits 5,4,3,2; finish with xor 2,1.
    #pragma unroll
    for (int a = 0; a < APB; ++a) {
        float w1r[8];
        #pragma unroll
        for (int k = 0; k < 8; ++k) {
            float lo = feat[a][k], hi = feat[a][k + 8];
            float lo2 = __shfl_xor(lo, 32, 64);
            float hi2 = __shfl_xor(hi, 32, 64);
            w1r[k] = (lane & 32) ? (hi + hi2) : (lo + lo2);
        }
        float w2r[4];
        #pragma unroll
        for (int k = 0; k < 4; ++k) {
            float lo = w1r[k], hi = w1r[k + 4];
            float lo2 = __shfl_xor(lo, 16, 64);
            float hi2 = __shfl_xor(hi, 16, 64);
            w2r[k] = (lane & 16) ? (hi + hi2) : (lo + lo2);
        }
        float w3r[2];
        #pragma unroll
        for (int k = 0; k < 2; ++k) {
            float lo = w2r[k], hi = w2r[k + 2];
            float lo2 = __shfl_xor(lo, 8, 64);
            float hi2 = __shfl_xor(hi, 8, 64);
            w3r[k] = (lane & 8) ? (hi + hi2) : (lo + lo2);
        }
        float lo2 = __shfl_xor(w3r[0], 4, 64);
        float hi2 = __shfl_xor(w3r[1], 4, 64);
        float w4 = (lane & 4) ? (w3r[1] + hi2) : (w3r[0] + lo2);
        w4 += __shfl_xor(w4, 2, 64);
        w4 += __shfl_xor(w4, 1, 64);
        if ((lane & 3) == 0) sfeat[wave][a][(lane >> 2) & 15] = w4;
    }
    __syncthreads();

    // MLP: waves 0,1; each handles 2 atoms (32 lanes per atom = hidden units)
    if (wave < 2) {
        int a = wave * 2 + (lane >> 5);
        int h = lane & 31;
        float acc = sb1[h];
        #pragma unroll
        for (int k = 0; k < N_RBF; ++k) {
            float fk = (sfeat[0][a][k] + sfeat[1][a][k] +
                        sfeat[2][a][k] + sfeat[3][a][k]) * UNSC;
            acc = fmaf(fk, sW1[k * N_HIDDEN + h], acc);
        }
        float sg = 1.0f / (1.0f + __builtin_amdgcn_exp2f(-acc * LOG2E));
        float e = acc * sg * sW2[h];
        #pragma unroll
        for (int off = 16; off > 0; off >>= 1) e += __shfl_xor(e, off, 64);
        if (h == 0) sen[a] = (abase + a < n) ? (e + b2[0]) : 0.0f;
    }
    __syncthreads();
    if (tid == 0) atomicAdd(out, (sen[0] + sen[1]) + (sen[2] + sen[3]));
}

extern "C" void kernel_launch(void* const* d_in, const int* in_sizes, int n_in,
                              void* d_out, int out_size, void* d_ws, size_t ws_size,
                              hipStream_t stream) {
    const float* pos = (const float*)d_in[0];
    const float* W1  = (const float*)d_in[1];
    const float* b1  = (const float*)d_in[2];
    const float* W2  = (const float*)d_in[3];
    const float* b2  = (const float*)d_in[4];
    float* out = (float*)d_out;

    const int n    = in_sizes[0] / 3;
    const int npad = (n + 255) & ~255;          // 4 quarters, each mult of 64
    const int quarter = npad >> 2;

    float4* ppos = (float4*)d_ws;               // 16*npad bytes of scratch

    hipMemsetAsync(out, 0, sizeof(float), stream);

    pack_kernel<<<(npad + 255) / 256, 256, 0, stream>>>(pos, ppos, n, npad);

    const int grid = (npad + APB - 1) / APB;    // covers all real atoms
    ag3sr_main<<<grid, BLOCK, 0, stream>>>(ppos, W1, b1, W2, b2, out, n, quarter);
}